// Round 1
// baseline (191.502 us; speedup 1.0000x reference)
//
#include <hip/hip_runtime.h>
#include <hip/hip_bf16.h>

// Problem constants (from reference)
#define PCR0   (-51.2f)
#define PCR1   (-51.2f)
#define VX_    (0.05f)
#define VY_    (0.05f)
#define STRIDE_ 4.0f
#define FW_    512
#define FH_    512
#define NCLS   10
#define NOBJ   500
#define OVERLAP_ 0.1f
#define MINRAD 2
#define RMAX_  16
#define BATCH_ 16
#define EPS_   1.1920928955078125e-07f   // np.finfo(float32).eps

// Flat output layout (all stored as float32 elements)
#define HEATMAP_ELEMS  (BATCH_ * NCLS * FH_ * FW_)       // 41,943,040
#define RETBOX_OFF     HEATMAP_ELEMS
#define RETBOX_ELEMS   (BATCH_ * NOBJ * 8)               // 64,000
#define INDS_OFF       (RETBOX_OFF + RETBOX_ELEMS)       // 42,007,040
#define INDS_ELEMS     (BATCH_ * NOBJ)                   // 8,000
#define MASK_OFF       (INDS_OFF + INDS_ELEMS)           // 42,015,040

// ---------------------------------------------------------------------------
// Kernel 1: zero the heatmap region with float4 stores (memory-bound floor).
// ---------------------------------------------------------------------------
__global__ void zero_heatmap(float4* __restrict__ hm4, int n4) {
    int idx = blockIdx.x * blockDim.x + threadIdx.x;
    int stride = gridDim.x * blockDim.x;
    float4 z = make_float4(0.f, 0.f, 0.f, 0.f);
    for (int i = idx; i < n4; i += stride) hm4[i] = z;
}

// ---------------------------------------------------------------------------
// Kernel 2: one block per object. Compute per-object scalars, write
// ret_boxes/inds/mask (thread 0), cooperatively paint gaussian via atomicMax.
// ---------------------------------------------------------------------------
__global__ __launch_bounds__(256) void paint_objects(
        const float* __restrict__ gt,   // (B, M, 8)
        float* __restrict__ out)        // flat output buffer
{
    const int obj = blockIdx.x;          // 0 .. B*M-1
    const int b   = obj / NOBJ;

    const float* g8 = gt + (size_t)obj * 8;
    const float x  = g8[0], y  = g8[1], z  = g8[2];
    const float dx = g8[3], dy = g8[4], dz = g8[5];
    const float hd = g8[6], clsf = g8[7];

    // coords (match reference op order: ((v - pcr)/V)/STRIDE, then clip)
    float coord_x = fminf(fmaxf((x - PCR0) / VX_ / STRIDE_, 0.f), (float)FW_ - 0.5f);
    float coord_y = fminf(fmaxf((y - PCR1) / VY_ / STRIDE_, 0.f), (float)FH_ - 0.5f);
    int cxi = (int)coord_x;   // trunc, coord >= 0
    int cyi = (int)coord_y;

    float dxf = dx / VX_ / STRIDE_;
    float dyf = dy / VY_ / STRIDE_;

    // _gaussian_radius(height=dxf, width=dyf, OVERLAP)
    const float h = dxf, w = dyf, o = OVERLAP_;
    float b1 = h + w;
    float c1 = w * h * (1.f - o) / (1.f + o);
    float r1 = (b1 + sqrtf(fmaxf(b1 * b1 - 4.f * c1, 0.f))) * 0.5f;
    float b2 = 2.f * (h + w);
    float c2 = (1.f - o) * w * h;
    float r2 = (b2 + sqrtf(fmaxf(b2 * b2 - 16.f * c2, 0.f))) * 0.5f;
    float a3 = 4.f * o;
    float b3 = -2.f * o * (h + w);
    float c3 = (o - 1.f) * w * h;
    float r3 = (b3 + sqrtf(fmaxf(b3 * b3 - 4.f * a3 * c3, 0.f))) / (2.f * a3);
    float radf = fminf(fminf(r1, r2), r3);
    int radius = (int)radf;                       // trunc toward zero (astype int32)
    radius = min(max(radius, MINRAD), RMAX_);

    bool valid = (dxf > 0.f) && (dyf > 0.f) &&
                 (cxi >= 0) && (cxi <= FW_) && (cyi >= 0) && (cyi <= FH_);

    if (threadIdx.x == 0) {
        float vf = valid ? 1.f : 0.f;
        float* rb = out + RETBOX_OFF + (size_t)obj * 8;
        rb[0] = (coord_x - (float)cxi) * vf;
        rb[1] = (coord_y - (float)cyi) * vf;
        rb[2] = z * vf;
        rb[3] = logf(fmaxf(dx, 1e-12f)) * vf;
        rb[4] = logf(fmaxf(dy, 1e-12f)) * vf;
        rb[5] = logf(fmaxf(dz, 1e-12f)) * vf;
        rb[6] = cosf(hd) * vf;
        rb[7] = sinf(hd) * vf;
        out[INDS_OFF + obj] = valid ? (float)(cyi * FW_ + cxi) : 0.f;
        out[MASK_OFF + obj] = vf;
    }

    if (!valid) return;

    // gaussian paint
    float sigma = (2.f * (float)radius + 1.f) / 6.f;
    float denom = 2.f * sigma * sigma;
    int side = 2 * radius + 1;
    int npos = side * side;

    int cls_i = (int)(clsf - 1.0f);
    int c = min(max(cls_i, 0), NCLS - 1);
    float* hm = out + ((size_t)b * NCLS + c) * (size_t)(FH_ * FW_);

    for (int idx = threadIdx.x; idx < npos; idx += blockDim.x) {
        int i = idx / side - radius;
        int j = idx % side - radius;
        float d2 = (float)(i * i + j * j);
        float gv = expf(-d2 / denom);
        if (gv < EPS_) continue;                  // g = where(g < eps, 0, g)
        int yy = cyi + i;
        int xx = cxi + j;
        if (yy < 0 || yy >= FH_ || xx < 0 || xx >= FW_) continue;
        atomicMax((int*)(hm + (size_t)yy * FW_ + xx), __float_as_int(gv));
    }
}

extern "C" void kernel_launch(void* const* d_in, const int* in_sizes, int n_in,
                              void* d_out, int out_size, void* d_ws, size_t ws_size,
                              hipStream_t stream) {
    const float* gt = (const float*)d_in[0];
    float* out = (float*)d_out;

    // 1) zero the heatmap region (harness re-poisons d_out to 0xAA each call)
    int n4 = HEATMAP_ELEMS / 4;                   // 10,485,760 float4
    zero_heatmap<<<4096, 256, 0, stream>>>((float4*)out, n4);

    // 2) per-object outputs + gaussian scatter-max
    paint_objects<<<BATCH_ * NOBJ, 256, 0, stream>>>(gt, out);
}

// Round 2
// 173.801 us; speedup vs baseline: 1.1018x; 1.1018x over previous
//
#include <hip/hip_runtime.h>
#include <hip/hip_bf16.h>

// Problem constants (from reference)
#define PCR0   (-51.2f)
#define PCR1   (-51.2f)
#define VX_    (0.05f)
#define VY_    (0.05f)
#define STRIDE_ 4.0f
#define FW_    512
#define FH_    512
#define NCLS   10
#define NOBJ   500
#define OVERLAP_ 0.1f
#define MINRAD 2
#define RMAX_  16
#define BATCH_ 16
#define EPS_   1.1920928955078125e-07f   // np.finfo(float32).eps

// Flat output layout (all stored as float32 elements)
#define HEATMAP_ELEMS  (BATCH_ * NCLS * FH_ * FW_)       // 41,943,040
#define RETBOX_OFF     HEATMAP_ELEMS
#define RETBOX_ELEMS   (BATCH_ * NOBJ * 8)               // 64,000
#define INDS_OFF       (RETBOX_OFF + RETBOX_ELEMS)       // 42,007,040
#define MASK_OFF       (INDS_OFF + BATCH_ * NOBJ)        // 42,015,040

// Tiling for the gather pass
#define TILE_  32
#define TPB_   (FW_ / TILE_)            // 16 tiles per row
#define NTILES (TPB_ * TPB_)            // 256 tiles per batch
#define CAP_   512                      // max objs per (batch,tile); <= NOBJ so safe

// ws layout
#define CNT_BYTES   (BATCH_ * NTILES * 4)                    // 16 KB
#define REC_OFF     CNT_BYTES
#define REC_BYTES   (BATCH_ * NOBJ * 32)                     // 256 KB
#define LIST_OFF    (REC_OFF + REC_BYTES)
#define LIST_BYTES  ((size_t)BATCH_ * NTILES * CAP_ * 4)     // 8 MB
#define WS_NEEDED   (LIST_OFF + LIST_BYTES)

struct __align__(16) ObjRec {
    int   cxi, cyi, rad, cls;   // cls clipped to [0, NCLS-1]
    float negInv;               // -1 / (2*sigma^2)
    int   valid;
    float pad0, pad1;
};

// ---------------------------------------------------------------------------
// Shared per-object math (identical arithmetic to the round-1 kernel so
// truncation boundaries don't move).
// ---------------------------------------------------------------------------
__device__ __forceinline__ void obj_params(const float* g8,
        float& coord_x, float& coord_y, int& cxi, int& cyi,
        int& radius, bool& valid)
{
    const float x = g8[0], y = g8[1];
    const float dx = g8[3], dy = g8[4];

    coord_x = fminf(fmaxf((x - PCR0) / VX_ / STRIDE_, 0.f), (float)FW_ - 0.5f);
    coord_y = fminf(fmaxf((y - PCR1) / VY_ / STRIDE_, 0.f), (float)FH_ - 0.5f);
    cxi = (int)coord_x;
    cyi = (int)coord_y;

    float dxf = dx / VX_ / STRIDE_;
    float dyf = dy / VY_ / STRIDE_;

    const float h = dxf, w = dyf, o = OVERLAP_;
    float b1 = h + w;
    float c1 = w * h * (1.f - o) / (1.f + o);
    float r1 = (b1 + sqrtf(fmaxf(b1 * b1 - 4.f * c1, 0.f))) * 0.5f;
    float b2 = 2.f * (h + w);
    float c2 = (1.f - o) * w * h;
    float r2 = (b2 + sqrtf(fmaxf(b2 * b2 - 16.f * c2, 0.f))) * 0.5f;
    float a3 = 4.f * o;
    float b3 = -2.f * o * (h + w);
    float c3 = (o - 1.f) * w * h;
    float r3 = (b3 + sqrtf(fmaxf(b3 * b3 - 4.f * a3 * c3, 0.f))) / (2.f * a3);
    float radf = fminf(fminf(r1, r2), r3);
    radius = (int)radf;
    radius = min(max(radius, MINRAD), RMAX_);

    valid = (dxf > 0.f) && (dyf > 0.f) &&
            (cxi >= 0) && (cxi <= FW_) && (cyi >= 0) && (cyi <= FH_);
}

// ---------------------------------------------------------------------------
// Phase A: one thread per object. Writes ret_boxes/inds/mask, the object
// record, and appends the object to each overlapped (batch,tile) bin.
// ---------------------------------------------------------------------------
__global__ void phaseA(const float* __restrict__ gt, float* __restrict__ out,
                       int* __restrict__ cnt, int* __restrict__ lists,
                       ObjRec* __restrict__ recs)
{
    int obj = blockIdx.x * blockDim.x + threadIdx.x;
    if (obj >= BATCH_ * NOBJ) return;
    int b = obj / NOBJ;

    const float* g8 = gt + (size_t)obj * 8;
    float coord_x, coord_y; int cxi, cyi, radius; bool valid;
    obj_params(g8, coord_x, coord_y, cxi, cyi, radius, valid);

    const float z = g8[2], dx = g8[3], dy = g8[4], dz = g8[5];
    const float hd = g8[6], clsf = g8[7];

    float vf = valid ? 1.f : 0.f;
    float* rb = out + RETBOX_OFF + (size_t)obj * 8;
    rb[0] = (coord_x - (float)cxi) * vf;
    rb[1] = (coord_y - (float)cyi) * vf;
    rb[2] = z * vf;
    rb[3] = logf(fmaxf(dx, 1e-12f)) * vf;
    rb[4] = logf(fmaxf(dy, 1e-12f)) * vf;
    rb[5] = logf(fmaxf(dz, 1e-12f)) * vf;
    rb[6] = cosf(hd) * vf;
    rb[7] = sinf(hd) * vf;
    out[INDS_OFF + obj] = valid ? (float)(cyi * FW_ + cxi) : 0.f;
    out[MASK_OFF + obj] = vf;

    int c = min(max((int)(clsf - 1.0f), 0), NCLS - 1);
    float sigma = (2.f * (float)radius + 1.f) / 6.f;
    float denom = 2.f * sigma * sigma;

    ObjRec r;
    r.cxi = cxi; r.cyi = cyi; r.rad = radius; r.cls = c;
    r.negInv = -1.0f / denom;
    r.valid = valid ? 1 : 0;
    r.pad0 = 0.f; r.pad1 = 0.f;
    recs[obj] = r;

    if (!valid) return;

    // stamp spans <= 33 px -> at most 2 tiles per dim
    int tx0 = max(cxi - radius, 0) >> 5;
    int tx1 = min(cxi + radius, FW_ - 1) >> 5;
    int ty0 = max(cyi - radius, 0) >> 5;
    int ty1 = min(cyi + radius, FH_ - 1) >> 5;
    for (int ty = ty0; ty <= ty1; ++ty) {
        for (int tx = tx0; tx <= tx1; ++tx) {
            int bin = b * NTILES + ty * TPB_ + tx;
            int pos = atomicAdd(&cnt[bin], 1);
            if (pos < CAP_) lists[(size_t)bin * CAP_ + pos] = obj;
        }
    }
}

// ---------------------------------------------------------------------------
// Phase B: one block per (batch, 32x32 tile). Each thread owns 4 consecutive
// px in a row, for all 10 classes, in registers. Gathers max over the bin's
// objects, then writes every heatmap cell exactly once (fused zeroing).
// ---------------------------------------------------------------------------
__global__ __launch_bounds__(256) void phaseB(
        float* __restrict__ out,
        const int* __restrict__ cnt, const int* __restrict__ lists,
        const ObjRec* __restrict__ recs)
{
    int bid  = blockIdx.x;           // 0 .. BATCH_*NTILES-1
    int b    = bid >> 8;             // / NTILES
    int tile = bid & (NTILES - 1);
    int ty = tile >> 4, tx = tile & (TPB_ - 1);

    int lr  = threadIdx.x >> 3;            // 0..31 local row
    int lc  = (threadIdx.x & 7) << 2;      // 0,4,...,28 local col
    int py  = (ty << 5) + lr;
    int px0 = (tx << 5) + lc;

    float acc[NCLS][4];
    #pragma unroll
    for (int c = 0; c < NCLS; ++c) {
        acc[c][0] = 0.f; acc[c][1] = 0.f; acc[c][2] = 0.f; acc[c][3] = 0.f;
    }

    int bin = b * NTILES + tile;
    int n = cnt[bin]; if (n > CAP_) n = CAP_;
    const int* lst = lists + (size_t)bin * CAP_;

    for (int k2 = 0; k2 < n; ++k2) {
        int o = lst[k2];
        ObjRec r = recs[o];
        int rad = r.rad;
        int ry = py - r.cyi;
        bool rowin = (ry >= -rad) && (ry <= rad);
        float fy = (float)(ry * ry);

        float val[4];
        #pragma unroll
        for (int k = 0; k < 4; ++k) {
            int rx = px0 + k - r.cxi;
            bool in = rowin && (rx >= -rad) && (rx <= rad);
            float d2 = fy + (float)(rx * rx);
            float g = expf(d2 * r.negInv);
            val[k] = (in && g >= EPS_) ? g : 0.f;
        }

        int cu = __builtin_amdgcn_readfirstlane(r.cls);  // wave-uniform class
        #pragma unroll
        for (int c = 0; c < NCLS; ++c) {
            if (c == cu) {
                #pragma unroll
                for (int k = 0; k < 4; ++k)
                    acc[c][k] = fmaxf(acc[c][k], val[k]);
            }
        }
    }

    size_t plane = (size_t)FH_ * FW_;
    size_t base  = (size_t)b * NCLS * plane + (size_t)py * FW_ + px0;
    #pragma unroll
    for (int c = 0; c < NCLS; ++c) {
        float4 v = make_float4(acc[c][0], acc[c][1], acc[c][2], acc[c][3]);
        *(float4*)(out + base + (size_t)c * plane) = v;
    }
}

// ---------------------------------------------------------------------------
// Fallback path (round-1 scatter version) in case ws_size is too small.
// ---------------------------------------------------------------------------
__global__ void zero_heatmap(float4* __restrict__ hm4, int n4) {
    int idx = blockIdx.x * blockDim.x + threadIdx.x;
    int stride = gridDim.x * blockDim.x;
    float4 z = make_float4(0.f, 0.f, 0.f, 0.f);
    for (int i = idx; i < n4; i += stride) hm4[i] = z;
}

__global__ __launch_bounds__(256) void paint_objects(
        const float* __restrict__ gt, float* __restrict__ out)
{
    const int obj = blockIdx.x;
    const int b   = obj / NOBJ;
    const float* g8 = gt + (size_t)obj * 8;

    float coord_x, coord_y; int cxi, cyi, radius; bool valid;
    obj_params(g8, coord_x, coord_y, cxi, cyi, radius, valid);

    const float z = g8[2], dx = g8[3], dy = g8[4], dz = g8[5];
    const float hd = g8[6], clsf = g8[7];

    if (threadIdx.x == 0) {
        float vf = valid ? 1.f : 0.f;
        float* rb = out + RETBOX_OFF + (size_t)obj * 8;
        rb[0] = (coord_x - (float)cxi) * vf;
        rb[1] = (coord_y - (float)cyi) * vf;
        rb[2] = z * vf;
        rb[3] = logf(fmaxf(dx, 1e-12f)) * vf;
        rb[4] = logf(fmaxf(dy, 1e-12f)) * vf;
        rb[5] = logf(fmaxf(dz, 1e-12f)) * vf;
        rb[6] = cosf(hd) * vf;
        rb[7] = sinf(hd) * vf;
        out[INDS_OFF + obj] = valid ? (float)(cyi * FW_ + cxi) : 0.f;
        out[MASK_OFF + obj] = vf;
    }
    if (!valid) return;

    float sigma = (2.f * (float)radius + 1.f) / 6.f;
    float denom = 2.f * sigma * sigma;
    int side = 2 * radius + 1;
    int npos = side * side;
    int c = min(max((int)(clsf - 1.0f), 0), NCLS - 1);
    float* hm = out + ((size_t)b * NCLS + c) * (size_t)(FH_ * FW_);

    for (int idx = threadIdx.x; idx < npos; idx += blockDim.x) {
        int i = idx / side - radius;
        int j = idx % side - radius;
        float d2 = (float)(i * i + j * j);
        float gv = expf(-d2 / denom);
        if (gv < EPS_) continue;
        int yy = cyi + i;
        int xx = cxi + j;
        if (yy < 0 || yy >= FH_ || xx < 0 || xx >= FW_) continue;
        atomicMax((int*)(hm + (size_t)yy * FW_ + xx), __float_as_int(gv));
    }
}

extern "C" void kernel_launch(void* const* d_in, const int* in_sizes, int n_in,
                              void* d_out, int out_size, void* d_ws, size_t ws_size,
                              hipStream_t stream) {
    const float* gt = (const float*)d_in[0];
    float* out = (float*)d_out;

    if (ws_size >= WS_NEEDED) {
        int* cnt      = (int*)d_ws;
        ObjRec* recs  = (ObjRec*)((char*)d_ws + REC_OFF);
        int* lists    = (int*)((char*)d_ws + LIST_OFF);

        // bin counters must start at zero (ws is poisoned to 0xAA each call)
        hipMemsetAsync(cnt, 0, CNT_BYTES, stream);

        phaseA<<<(BATCH_ * NOBJ + 255) / 256, 256, 0, stream>>>(gt, out, cnt, lists, recs);
        phaseB<<<BATCH_ * NTILES, 256, 0, stream>>>(out, cnt, lists, recs);
    } else {
        // fallback: scatter path
        int n4 = HEATMAP_ELEMS / 4;
        zero_heatmap<<<4096, 256, 0, stream>>>((float4*)out, n4);
        paint_objects<<<BATCH_ * NOBJ, 256, 0, stream>>>(gt, out);
    }
}

// Round 3
// 170.694 us; speedup vs baseline: 1.1219x; 1.0182x over previous
//
#include <hip/hip_runtime.h>
#include <hip/hip_bf16.h>

// Problem constants (from reference)
#define PCR0   (-51.2f)
#define PCR1   (-51.2f)
#define VX_    (0.05f)
#define VY_    (0.05f)
#define STRIDE_ 4.0f
#define FW_    512
#define FH_    512
#define NCLS   10
#define NOBJ   500
#define OVERLAP_ 0.1f
#define MINRAD 2
#define RMAX_  16
#define BATCH_ 16
#define EPS_   1.1920928955078125e-07f   // np.finfo(float32).eps

// Flat output layout (all stored as float32 elements)
#define HEATMAP_ELEMS  (BATCH_ * NCLS * FH_ * FW_)       // 41,943,040
#define RETBOX_OFF     HEATMAP_ELEMS
#define RETBOX_ELEMS   (BATCH_ * NOBJ * 8)               // 64,000
#define INDS_OFF       (RETBOX_OFF + RETBOX_ELEMS)       // 42,007,040
#define MASK_OFF       (INDS_OFF + BATCH_ * NOBJ)        // 42,015,040

// Binning: (batch, 32-row band, class). Block = one contiguous 64 KB slab.
#define BAND_  32
#define NBAND  (FH_ / BAND_)                 // 16
#define NBINS  (BATCH_ * NCLS * NBAND)       // 2560
#define CAPB   NOBJ                          // worst case: all objs of a batch in one bin

// ws layout
#define CNT_BYTES   (NBINS * 4)                          // 10,240
#define REC_OFF     CNT_BYTES                            // 16B-aligned (10240 = 640*16)
#define REC_BYTES   (BATCH_ * NOBJ * 16)                 // 128,000 (int4 per obj)
#define LIST_OFF    (REC_OFF + REC_BYTES)                // 138,240
#define LIST_BYTES  ((size_t)NBINS * CAPB * 4)           // 5,120,000
#define WS_NEEDED   (LIST_OFF + LIST_BYTES)              // ~5.26 MB

// ---------------------------------------------------------------------------
// Shared per-object math (identical arithmetic to the round-1 kernel so
// truncation boundaries don't move).
// ---------------------------------------------------------------------------
__device__ __forceinline__ void obj_params(const float* g8,
        float& coord_x, float& coord_y, int& cxi, int& cyi,
        int& radius, bool& valid)
{
    const float x = g8[0], y = g8[1];
    const float dx = g8[3], dy = g8[4];

    coord_x = fminf(fmaxf((x - PCR0) / VX_ / STRIDE_, 0.f), (float)FW_ - 0.5f);
    coord_y = fminf(fmaxf((y - PCR1) / VY_ / STRIDE_, 0.f), (float)FH_ - 0.5f);
    cxi = (int)coord_x;
    cyi = (int)coord_y;

    float dxf = dx / VX_ / STRIDE_;
    float dyf = dy / VY_ / STRIDE_;

    const float h = dxf, w = dyf, o = OVERLAP_;
    float b1 = h + w;
    float c1 = w * h * (1.f - o) / (1.f + o);
    float r1 = (b1 + sqrtf(fmaxf(b1 * b1 - 4.f * c1, 0.f))) * 0.5f;
    float b2 = 2.f * (h + w);
    float c2 = (1.f - o) * w * h;
    float r2 = (b2 + sqrtf(fmaxf(b2 * b2 - 16.f * c2, 0.f))) * 0.5f;
    float a3 = 4.f * o;
    float b3 = -2.f * o * (h + w);
    float c3 = (o - 1.f) * w * h;
    float r3 = (b3 + sqrtf(fmaxf(b3 * b3 - 4.f * a3 * c3, 0.f))) / (2.f * a3);
    float radf = fminf(fminf(r1, r2), r3);
    radius = (int)radf;
    radius = min(max(radius, MINRAD), RMAX_);

    valid = (dxf > 0.f) && (dyf > 0.f) &&
            (cxi >= 0) && (cxi <= FW_) && (cyi >= 0) && (cyi <= FH_);
}

// ---------------------------------------------------------------------------
// Phase A: one thread per object. Writes ret_boxes/inds/mask, the object
// record, and appends the object to each overlapped (batch,band,class) bin.
// ---------------------------------------------------------------------------
__global__ void phaseA(const float* __restrict__ gt, float* __restrict__ out,
                       int* __restrict__ cnt, int* __restrict__ lists,
                       int4* __restrict__ recs)
{
    int obj = blockIdx.x * blockDim.x + threadIdx.x;
    if (obj >= BATCH_ * NOBJ) return;
    int b = obj / NOBJ;

    const float* g8 = gt + (size_t)obj * 8;
    float coord_x, coord_y; int cxi, cyi, radius; bool valid;
    obj_params(g8, coord_x, coord_y, cxi, cyi, radius, valid);

    const float z = g8[2], dx = g8[3], dy = g8[4], dz = g8[5];
    const float hd = g8[6], clsf = g8[7];

    float vf = valid ? 1.f : 0.f;
    float* rb = out + RETBOX_OFF + (size_t)obj * 8;
    rb[0] = (coord_x - (float)cxi) * vf;
    rb[1] = (coord_y - (float)cyi) * vf;
    rb[2] = z * vf;
    rb[3] = logf(fmaxf(dx, 1e-12f)) * vf;
    rb[4] = logf(fmaxf(dy, 1e-12f)) * vf;
    rb[5] = logf(fmaxf(dz, 1e-12f)) * vf;
    rb[6] = cosf(hd) * vf;
    rb[7] = sinf(hd) * vf;
    out[INDS_OFF + obj] = valid ? (float)(cyi * FW_ + cxi) : 0.f;
    out[MASK_OFF + obj] = vf;

    int c = min(max((int)(clsf - 1.0f), 0), NCLS - 1);
    float sigma = (2.f * (float)radius + 1.f) / 6.f;
    float negInv = -1.0f / (2.f * sigma * sigma);

    int4 r;
    r.x = cxi; r.y = cyi; r.z = radius; r.w = __float_as_int(negInv);
    recs[obj] = r;

    if (!valid) return;

    // stamp spans <= 33 rows -> at most 3 bands
    int ty0 = max(cyi - radius, 0) >> 5;
    int ty1 = min(cyi + radius, FH_ - 1) >> 5;
    int binbase = (b * NCLS + c) * NBAND;
    for (int ty = ty0; ty <= ty1; ++ty) {
        int bin = binbase + ty;
        int pos = atomicAdd(&cnt[bin], 1);
        if (pos < CAPB) lists[(size_t)bin * CAPB + pos] = obj;
    }
}

// ---------------------------------------------------------------------------
// Phase B: one 512-thread block per (batch, class, band) = one contiguous
// 32x512 slab (64 KB) of one class plane. Gather max over the bin's objects
// (separable gaussian, wave-uniform early-outs), write every cell once.
// blockIdx.x IS both the bin index and the linear slab index.
// ---------------------------------------------------------------------------
__global__ __launch_bounds__(512) void phaseB(
        float* __restrict__ out,
        const int* __restrict__ cnt, const int* __restrict__ lists,
        const int4* __restrict__ recs)
{
    const int bid = blockIdx.x;                 // 0 .. NBINS-1
    const int t   = threadIdx.x;
    const int col0  = (t & 127) << 2;           // 0,4,...,508
    // wave-uniform helpers (readfirstlane so the compiler emits scalar branches)
    const int r0    = __builtin_amdgcn_readfirstlane(t >> 7);          // 0..3
    const int wbase = __builtin_amdgcn_readfirstlane(((t >> 6) & 1) << 8); // 0 or 256
    const int y0    = (bid & (NBAND - 1)) << 5; // first row of band within plane

    float acc[8][4];
    #pragma unroll
    for (int s = 0; s < 8; ++s) {
        acc[s][0] = 0.f; acc[s][1] = 0.f; acc[s][2] = 0.f; acc[s][3] = 0.f;
    }

    int n = cnt[bid]; if (n > CAPB) n = CAPB;
    const int* lst = lists + (size_t)bid * CAPB;

    for (int it = 0; it < n; ++it) {
        int o = __builtin_amdgcn_readfirstlane(lst[it]);
        int4 r = recs[o];
        int cxi   = __builtin_amdgcn_readfirstlane(r.x);
        int cyi   = __builtin_amdgcn_readfirstlane(r.y);
        int rad   = __builtin_amdgcn_readfirstlane(r.z);
        float negInv = __int_as_float(__builtin_amdgcn_readfirstlane(r.w));

        // wave-uniform column-range early-out (wave covers cols [wbase, wbase+255])
        if (cxi + rad < wbase || cxi - rad > wbase + 255) continue;

        float cexp[4]; bool colin[4];
        #pragma unroll
        for (int k = 0; k < 4; ++k) {
            int rx = col0 + k - cxi;
            colin[k] = (rx >= -rad) && (rx <= rad);
            cexp[k]  = __expf((float)(rx * rx) * negInv);
        }

        #pragma unroll
        for (int s = 0; s < 8; ++s) {
            int ry = y0 + 4 * s + r0 - cyi;     // wave-uniform
            if (ry < -rad || ry > rad) continue; // scalar branch
            float rexp = __expf((float)(ry * ry) * negInv);
            #pragma unroll
            for (int k = 0; k < 4; ++k) {
                float g = rexp * cexp[k];
                bool ok = colin[k] && (g >= EPS_);
                acc[s][k] = ok ? fmaxf(acc[s][k], g) : acc[s][k];
            }
        }
    }

    // contiguous 64 KB store: wave writes 1 KB runs, block covers the slab
    float4* out4 = (float4*)(out + (size_t)bid * (BAND_ * FW_));
    #pragma unroll
    for (int s = 0; s < 8; ++s)
        out4[s * 512 + t] = make_float4(acc[s][0], acc[s][1], acc[s][2], acc[s][3]);
}

// ---------------------------------------------------------------------------
// Fallback path (round-1 scatter version) in case ws_size is too small.
// ---------------------------------------------------------------------------
__global__ void zero_heatmap(float4* __restrict__ hm4, int n4) {
    int idx = blockIdx.x * blockDim.x + threadIdx.x;
    int stride = gridDim.x * blockDim.x;
    float4 z = make_float4(0.f, 0.f, 0.f, 0.f);
    for (int i = idx; i < n4; i += stride) hm4[i] = z;
}

__global__ __launch_bounds__(256) void paint_objects(
        const float* __restrict__ gt, float* __restrict__ out)
{
    const int obj = blockIdx.x;
    const int b   = obj / NOBJ;
    const float* g8 = gt + (size_t)obj * 8;

    float coord_x, coord_y; int cxi, cyi, radius; bool valid;
    obj_params(g8, coord_x, coord_y, cxi, cyi, radius, valid);

    const float z = g8[2], dx = g8[3], dy = g8[4], dz = g8[5];
    const float hd = g8[6], clsf = g8[7];

    if (threadIdx.x == 0) {
        float vf = valid ? 1.f : 0.f;
        float* rb = out + RETBOX_OFF + (size_t)obj * 8;
        rb[0] = (coord_x - (float)cxi) * vf;
        rb[1] = (coord_y - (float)cyi) * vf;
        rb[2] = z * vf;
        rb[3] = logf(fmaxf(dx, 1e-12f)) * vf;
        rb[4] = logf(fmaxf(dy, 1e-12f)) * vf;
        rb[5] = logf(fmaxf(dz, 1e-12f)) * vf;
        rb[6] = cosf(hd) * vf;
        rb[7] = sinf(hd) * vf;
        out[INDS_OFF + obj] = valid ? (float)(cyi * FW_ + cxi) : 0.f;
        out[MASK_OFF + obj] = vf;
    }
    if (!valid) return;

    float sigma = (2.f * (float)radius + 1.f) / 6.f;
    float denom = 2.f * sigma * sigma;
    int side = 2 * radius + 1;
    int npos = side * side;
    int c = min(max((int)(clsf - 1.0f), 0), NCLS - 1);
    float* hm = out + ((size_t)b * NCLS + c) * (size_t)(FH_ * FW_);

    for (int idx = threadIdx.x; idx < npos; idx += blockDim.x) {
        int i = idx / side - radius;
        int j = idx % side - radius;
        float d2 = (float)(i * i + j * j);
        float gv = expf(-d2 / denom);
        if (gv < EPS_) continue;
        int yy = cyi + i;
        int xx = cxi + j;
        if (yy < 0 || yy >= FH_ || xx < 0 || xx >= FW_) continue;
        atomicMax((int*)(hm + (size_t)yy * FW_ + xx), __float_as_int(gv));
    }
}

extern "C" void kernel_launch(void* const* d_in, const int* in_sizes, int n_in,
                              void* d_out, int out_size, void* d_ws, size_t ws_size,
                              hipStream_t stream) {
    const float* gt = (const float*)d_in[0];
    float* out = (float*)d_out;

    if (ws_size >= WS_NEEDED) {
        int* cnt     = (int*)d_ws;
        int4* recs   = (int4*)((char*)d_ws + REC_OFF);
        int* lists   = (int*)((char*)d_ws + LIST_OFF);

        // bin counters must start at zero (ws is poisoned to 0xAA each call)
        hipMemsetAsync(cnt, 0, CNT_BYTES, stream);

        phaseA<<<(BATCH_ * NOBJ + 255) / 256, 256, 0, stream>>>(gt, out, cnt, lists, recs);
        phaseB<<<NBINS, 512, 0, stream>>>(out, cnt, lists, recs);
    } else {
        // fallback: scatter path
        int n4 = HEATMAP_ELEMS / 4;
        zero_heatmap<<<4096, 256, 0, stream>>>((float4*)out, n4);
        paint_objects<<<BATCH_ * NOBJ, 256, 0, stream>>>(gt, out);
    }
}

// Round 4
// 168.179 us; speedup vs baseline: 1.1387x; 1.0150x over previous
//
#include <hip/hip_runtime.h>
#include <hip/hip_bf16.h>

// Problem constants (from reference)
#define PCR0   (-51.2f)
#define PCR1   (-51.2f)
#define VX_    (0.05f)
#define VY_    (0.05f)
#define STRIDE_ 4.0f
#define FW_    512
#define FH_    512
#define NCLS   10
#define NOBJ   500
#define OVERLAP_ 0.1f
#define MINRAD 2
#define RMAX_  16
#define BATCH_ 16
#define EPS_   1.1920928955078125e-07f   // np.finfo(float32).eps

// Flat output layout (all stored as float32 elements)
#define HEATMAP_ELEMS  (BATCH_ * NCLS * FH_ * FW_)       // 41,943,040
#define RETBOX_OFF     HEATMAP_ELEMS
#define RETBOX_ELEMS   (BATCH_ * NOBJ * 8)               // 64,000
#define INDS_OFF       (RETBOX_OFF + RETBOX_ELEMS)       // 42,007,040
#define MASK_OFF       (INDS_OFF + BATCH_ * NOBJ)        // 42,015,040

// Block = one (batch, class, 32-row band) = one contiguous 64 KB slab.
#define BAND_  32
#define NBAND  (FH_ / BAND_)                 // 16
#define NBINS  (BATCH_ * NCLS * NBAND)       // 2560

// ---------------------------------------------------------------------------
// Per-object math (identical arithmetic to rounds 1-3 so truncation
// boundaries don't move).
// ---------------------------------------------------------------------------
__device__ __forceinline__ void obj_params(const float* g8,
        float& coord_x, float& coord_y, int& cxi, int& cyi,
        int& radius, bool& valid)
{
    const float x = g8[0], y = g8[1];
    const float dx = g8[3], dy = g8[4];

    coord_x = fminf(fmaxf((x - PCR0) / VX_ / STRIDE_, 0.f), (float)FW_ - 0.5f);
    coord_y = fminf(fmaxf((y - PCR1) / VY_ / STRIDE_, 0.f), (float)FH_ - 0.5f);
    cxi = (int)coord_x;
    cyi = (int)coord_y;

    float dxf = dx / VX_ / STRIDE_;
    float dyf = dy / VY_ / STRIDE_;

    const float h = dxf, w = dyf, o = OVERLAP_;
    float b1 = h + w;
    float c1 = w * h * (1.f - o) / (1.f + o);
    float r1 = (b1 + sqrtf(fmaxf(b1 * b1 - 4.f * c1, 0.f))) * 0.5f;
    float b2 = 2.f * (h + w);
    float c2 = (1.f - o) * w * h;
    float r2 = (b2 + sqrtf(fmaxf(b2 * b2 - 16.f * c2, 0.f))) * 0.5f;
    float a3 = 4.f * o;
    float b3 = -2.f * o * (h + w);
    float c3 = (o - 1.f) * w * h;
    float r3 = (b3 + sqrtf(fmaxf(b3 * b3 - 4.f * a3 * c3, 0.f))) / (2.f * a3);
    float radf = fminf(fminf(r1, r2), r3);
    radius = (int)radf;
    radius = min(max(radius, MINRAD), RMAX_);

    valid = (dxf > 0.f) && (dyf > 0.f) &&
            (cxi >= 0) && (cxi <= FW_) && (cyi >= 0) && (cyi <= FH_);
}

// ---------------------------------------------------------------------------
// Single fused kernel. One 512-thread block per (batch, class, band):
//   1) threads 0..499 scan the batch's objects (16 KB, L1-hot), filter to
//      this block's class+band, append records to an LDS list; the 16
//      (class==0, band==0) blocks also write ret_boxes/inds/mask.
//   2) gather max over the LDS list (separable gaussian, wave-uniform
//      early-outs), write the contiguous 64 KB slab exactly once.
// blockIdx.x IS the linear slab index, so stores stream sequentially.
// ---------------------------------------------------------------------------
__global__ __launch_bounds__(512) void fused(
        const float* __restrict__ gt, float* __restrict__ out)
{
    const int bid  = blockIdx.x;                 // 0 .. NBINS-1
    const int b    = bid / (NCLS * NBAND);
    const int rem  = bid - b * (NCLS * NBAND);
    const int myc  = rem >> 4;                   // / NBAND
    const int band = rem & (NBAND - 1);
    const int y0   = band << 5;

    __shared__ int  s_cnt;
    __shared__ int4 s_rec[NOBJ];

    if (threadIdx.x == 0) s_cnt = 0;
    __syncthreads();

    const int t = threadIdx.x;
    if (t < NOBJ) {
        const int obj = b * NOBJ + t;
        const float* g8 = gt + (size_t)obj * 8;
        float coord_x, coord_y; int cxi, cyi, radius; bool valid;
        obj_params(g8, coord_x, coord_y, cxi, cyi, radius, valid);
        int c = min(max((int)(g8[7] - 1.0f), 0), NCLS - 1);

        if (myc == 0 && band == 0) {
            // designated writer block for this batch: per-object outputs
            const float z = g8[2], dx = g8[3], dy = g8[4], dz = g8[5];
            const float hd = g8[6];
            float vf = valid ? 1.f : 0.f;
            float* rb = out + RETBOX_OFF + (size_t)obj * 8;
            rb[0] = (coord_x - (float)cxi) * vf;
            rb[1] = (coord_y - (float)cyi) * vf;
            rb[2] = z * vf;
            rb[3] = logf(fmaxf(dx, 1e-12f)) * vf;
            rb[4] = logf(fmaxf(dy, 1e-12f)) * vf;
            rb[5] = logf(fmaxf(dz, 1e-12f)) * vf;
            rb[6] = cosf(hd) * vf;
            rb[7] = sinf(hd) * vf;
            out[INDS_OFF + obj] = valid ? (float)(cyi * FW_ + cxi) : 0.f;
            out[MASK_OFF + obj] = vf;
        }

        // band overlap: [cyi-radius, cyi+radius] intersects [y0, y0+31]
        if (valid && c == myc &&
            (cyi + radius >= y0) && (cyi - radius <= y0 + BAND_ - 1)) {
            float sigma = (2.f * (float)radius + 1.f) / 6.f;
            float negInv = -1.0f / (2.f * sigma * sigma);
            int pos = atomicAdd(&s_cnt, 1);
            s_rec[pos] = make_int4(cxi, cyi, radius, __float_as_int(negInv));
        }
    }
    __syncthreads();

    const int col0  = (t & 127) << 2;           // 0,4,...,508
    const int r0    = __builtin_amdgcn_readfirstlane(t >> 7);              // 0..3
    const int wbase = __builtin_amdgcn_readfirstlane(((t >> 6) & 1) << 8); // 0 or 256

    float acc[8][4];
    #pragma unroll
    for (int s = 0; s < 8; ++s) {
        acc[s][0] = 0.f; acc[s][1] = 0.f; acc[s][2] = 0.f; acc[s][3] = 0.f;
    }

    const int n = s_cnt;
    for (int it = 0; it < n; ++it) {
        int4 r = s_rec[it];                      // broadcast LDS read
        int cxi   = __builtin_amdgcn_readfirstlane(r.x);
        int cyi   = __builtin_amdgcn_readfirstlane(r.y);
        int rad   = __builtin_amdgcn_readfirstlane(r.z);
        float negInv = __int_as_float(__builtin_amdgcn_readfirstlane(r.w));

        // wave-uniform column-range early-out (wave covers cols [wbase, wbase+255])
        if (cxi + rad < wbase || cxi - rad > wbase + 255) continue;

        float cexp[4]; bool colin[4];
        #pragma unroll
        for (int k = 0; k < 4; ++k) {
            int rx = col0 + k - cxi;
            colin[k] = (rx >= -rad) && (rx <= rad);
            cexp[k]  = __expf((float)(rx * rx) * negInv);
        }

        #pragma unroll
        for (int s = 0; s < 8; ++s) {
            int ry = y0 + 4 * s + r0 - cyi;      // wave-uniform
            if (ry < -rad || ry > rad) continue; // scalar branch
            float rexp = __expf((float)(ry * ry) * negInv);
            #pragma unroll
            for (int k = 0; k < 4; ++k) {
                float g = rexp * cexp[k];
                bool ok = colin[k] && (g >= EPS_);
                acc[s][k] = ok ? fmaxf(acc[s][k], g) : acc[s][k];
            }
        }
    }

    // contiguous 64 KB slab store; blockIdx order == memory order
    float4* out4 = (float4*)(out + (size_t)bid * (BAND_ * FW_));
    #pragma unroll
    for (int s = 0; s < 8; ++s)
        out4[s * 512 + t] = make_float4(acc[s][0], acc[s][1], acc[s][2], acc[s][3]);
}

extern "C" void kernel_launch(void* const* d_in, const int* in_sizes, int n_in,
                              void* d_out, int out_size, void* d_ws, size_t ws_size,
                              hipStream_t stream) {
    const float* gt = (const float*)d_in[0];
    float* out = (float*)d_out;
    fused<<<NBINS, 512, 0, stream>>>(gt, out);
}